// Round 1
// baseline (596.611 us; speedup 1.0000x reference)
//
#include <hip/hip_runtime.h>

#define N_NODES 50000
#define N_EDGES 800000
#define HID 128
#define OUT_STRIDE 512

// ---------------- CSR build ----------------

__global__ void deg_kernel(const int* __restrict__ dst, int* __restrict__ deg, int E) {
    int e = blockIdx.x * 256 + threadIdx.x;
    if (e < E) atomicAdd(&deg[dst[e]], 1);
}

// single-block exclusive scan over deg -> off, plus inv_deg
__global__ void scan_kernel(const int* __restrict__ deg, int* __restrict__ off,
                            float* __restrict__ inv_deg, int N) {
    __shared__ int sums[1024];
    int t = threadIdx.x;
    int chunk = (N + 1023) >> 10;
    int start = t * chunk;
    int end = min(start + chunk, N);
    int s = 0;
    for (int i = start; i < end; ++i) s += deg[i];
    sums[t] = s;
    __syncthreads();
    for (int o = 1; o < 1024; o <<= 1) {
        int v = (t >= o) ? sums[t - o] : 0;
        __syncthreads();
        sums[t] += v;
        __syncthreads();
    }
    int run = sums[t] - s;  // exclusive prefix of this thread's chunk
    for (int i = start; i < end; ++i) {
        off[i] = run;
        int d = deg[i];
        run += d;
        inv_deg[i] = 1.0f / (float)max(d, 1);
    }
}

__global__ void fill_kernel(const int* __restrict__ src, const int* __restrict__ dst,
                            const int* __restrict__ off, int* __restrict__ cursor,
                            int* __restrict__ csr_src, int E) {
    int e = blockIdx.x * 256 + threadIdx.x;
    if (e < E) {
        int d = dst[e];
        int p = atomicAdd(&cursor[d], 1);
        csr_src[off[d] + p] = src[e];
    }
}

// ---------------- mean aggregation: one wave per node ----------------
// h row stride = OUT_STRIDE (h lives inside the output buffer)

__global__ void agg_kernel(const float* __restrict__ h,
                           const int* __restrict__ off, const int* __restrict__ deg,
                           const float* __restrict__ inv_deg,
                           const int* __restrict__ csr_src,
                           float* __restrict__ agg) {
    int wave = threadIdx.x >> 6;   // 0..3
    int lane = threadIdx.x & 63;
    int n = blockIdx.x * 4 + wave;
    if (n >= N_NODES) return;
    int start = off[n];
    int cnt = deg[n];
    float ax = 0.f, ay = 0.f;
    for (int e = 0; e < cnt; ++e) {
        int s = csr_src[start + e];
        const float2 v = *(const float2*)(h + (size_t)s * OUT_STRIDE + 2 * lane);
        ax += v.x; ay += v.y;
    }
    float sc = inv_deg[n];
    float2* o = (float2*)(agg + (size_t)n * HID) + lane;
    *o = make_float2(ax * sc, ay * sc);
}

// ---------------- GEMM + ReLU: C[:, coff:coff+128] = relu(A @ W) ----------------
// A: [nrows,128] contiguous. W: [128,128] k-major. C row stride OUT_STRIDE.
// Tile 64 rows x 64 cols per block (blockIdx.y = col half), 256 threads,
// 4x4 register micro-tile, A-tile + W-half staged in LDS (32KB + 32KB).

__global__ __launch_bounds__(256) void gemm_relu_kernel(
        const float* __restrict__ A, const float* __restrict__ W,
        float* __restrict__ C, int coff, int nrows) {
    __shared__ float Wl[128 * 64];   // [k][c-half]
    __shared__ float Al[64 * 128];   // [r][k]
    int tid = threadIdx.x;
    int r0 = blockIdx.x * 64;
    int ch = blockIdx.y;             // 0 or 1: column half

    // load W half: 8192 floats, 8 float4 per thread, coalesced
    #pragma unroll
    for (int i = 0; i < 8; ++i) {
        int o = i * 1024 + tid * 4;
        int k = o >> 6, c = o & 63;
        *(float4*)&Wl[o] = *(const float4*)&W[k * 128 + ch * 64 + c];
    }
    // load A tile: 8192 floats, guarded
    int limit = nrows * 128;
    #pragma unroll
    for (int i = 0; i < 8; ++i) {
        int o = i * 1024 + tid * 4;
        int g = r0 * 128 + o;
        float4 v = make_float4(0.f, 0.f, 0.f, 0.f);
        if (g < limit) v = *(const float4*)&A[g];
        *(float4*)&Al[o] = v;
    }
    __syncthreads();

    int cg = tid & 15;  int col = cg * 4;      // 16 col-groups x 4 cols = 64
    int rg = tid >> 4;                          // 16 row-groups x 4 rows = 64
    float acc[4][4] = {};

    for (int k = 0; k < 128; k += 4) {
        float4 w[4];
        #pragma unroll
        for (int kk = 0; kk < 4; ++kk)
            w[kk] = *(const float4*)&Wl[(k + kk) * 64 + col];
        #pragma unroll
        for (int j = 0; j < 4; ++j) {
            float4 a = *(const float4*)&Al[(rg * 4 + j) * 128 + k];
            float av[4] = {a.x, a.y, a.z, a.w};
            #pragma unroll
            for (int kk = 0; kk < 4; ++kk) {
                const float* wv = (const float*)&w[kk];
                acc[j][0] += av[kk] * wv[0];
                acc[j][1] += av[kk] * wv[1];
                acc[j][2] += av[kk] * wv[2];
                acc[j][3] += av[kk] * wv[3];
            }
        }
    }

    #pragma unroll
    for (int j = 0; j < 4; ++j) {
        int r = r0 + rg * 4 + j;
        if (r < nrows) {
            float4 o;
            o.x = fmaxf(acc[j][0], 0.f);
            o.y = fmaxf(acc[j][1], 0.f);
            o.z = fmaxf(acc[j][2], 0.f);
            o.w = fmaxf(acc[j][3], 0.f);
            *(float4*)&C[(size_t)r * OUT_STRIDE + coff + ch * 64 + col] = o;
        }
    }
}

extern "C" void kernel_launch(void* const* d_in, const int* in_sizes, int n_in,
                              void* d_out, int out_size, void* d_ws, size_t ws_size,
                              hipStream_t stream) {
    const float* feat = (const float*)d_in[0];
    const int*   src  = (const int*)d_in[1];
    const int*   dst  = (const int*)d_in[2];
    const float* W0   = (const float*)d_in[3];
    const float* Ws   = (const float*)d_in[4];
    float* out = (float*)d_out;

    // workspace carve-up (~29.6 MB)
    char* p = (char*)d_ws;
    float* agg   = (float*)p;           p += (size_t)N_NODES * HID * sizeof(float);
    int*   deg   = (int*)p;             p += (size_t)N_NODES * sizeof(int);
    int*   cursor= (int*)p;             p += (size_t)N_NODES * sizeof(int);
    int*   off   = (int*)p;             p += (size_t)N_NODES * sizeof(int);
    int*   csr   = (int*)p;             p += (size_t)N_EDGES * sizeof(int);
    float* invd  = (float*)p;

    // deg and cursor are contiguous: zero both in one memset
    hipMemsetAsync(deg, 0, (size_t)N_NODES * 2 * sizeof(int), stream);

    int eblocks = (N_EDGES + 255) / 256;
    deg_kernel<<<eblocks, 256, 0, stream>>>(dst, deg, N_EDGES);
    scan_kernel<<<1, 1024, 0, stream>>>(deg, off, invd, N_NODES);
    fill_kernel<<<eblocks, 256, 0, stream>>>(src, dst, off, cursor, csr, N_EDGES);

    dim3 ggrid((N_NODES + 63) / 64, 2);
    // h0 = relu(feat @ W0) -> out[:, 0:128]
    gemm_relu_kernel<<<ggrid, 256, 0, stream>>>(feat, W0, out, 0, N_NODES);

    int ablocks = (N_NODES + 3) / 4;
    for (int l = 0; l < 3; ++l) {
        agg_kernel<<<ablocks, 256, 0, stream>>>(out + l * HID, off, deg, invd, csr, agg);
        gemm_relu_kernel<<<ggrid, 256, 0, stream>>>(agg, Ws + (size_t)l * HID * HID,
                                                    out, (l + 1) * HID, N_NODES);
    }
}

// Round 2
// 494.515 us; speedup vs baseline: 1.2065x; 1.2065x over previous
//
#include <hip/hip_runtime.h>

#define N_NODES 50000
#define N_EDGES 800000
#define HID 128
#define OUT_STRIDE 512

#define SCAN_CHUNK 512
#define SCAN_BLOCKS ((N_NODES + SCAN_CHUNK - 1) / SCAN_CHUNK)   // 98

// ---------------- CSR build ----------------

__global__ void deg_kernel(const int* __restrict__ dst, int* __restrict__ deg, int E) {
    int e = blockIdx.x * 256 + threadIdx.x;
    if (e < E) atomicAdd(&deg[dst[e]], 1);
}

// phase 1: per-block sum of a 512-wide chunk of deg
__global__ __launch_bounds__(SCAN_CHUNK) void blocksum_kernel(
        const int* __restrict__ deg, int* __restrict__ bsum) {
    __shared__ int ws[SCAN_CHUNK / 64];
    int i = blockIdx.x * SCAN_CHUNK + threadIdx.x;
    int v = (i < N_NODES) ? deg[i] : 0;
    #pragma unroll
    for (int o = 32; o > 0; o >>= 1) v += __shfl_down(v, o, 64);
    if ((threadIdx.x & 63) == 0) ws[threadIdx.x >> 6] = v;
    __syncthreads();
    if (threadIdx.x == 0) {
        int s = 0;
        #pragma unroll
        for (int w = 0; w < SCAN_CHUNK / 64; ++w) s += ws[w];
        bsum[blockIdx.x] = s;
    }
}

// phase 2: exclusive scan of the SCAN_BLOCKS block sums (tiny, one block)
__global__ void scanb_kernel(int* __restrict__ bsum) {
    __shared__ int s[128];
    int t = threadIdx.x;
    s[t] = (t < SCAN_BLOCKS) ? bsum[t] : 0;
    __syncthreads();
    #pragma unroll
    for (int o = 1; o < 128; o <<= 1) {
        int v = (t >= o) ? s[t - o] : 0;
        __syncthreads();
        s[t] += v;
        __syncthreads();
    }
    if (t < SCAN_BLOCKS) bsum[t] = (t == 0) ? 0 : s[t - 1];
}

// phase 3: block-local exclusive scan + block prefix -> off, inv_deg
__global__ __launch_bounds__(SCAN_CHUNK) void scanfin_kernel(
        const int* __restrict__ deg, const int* __restrict__ bsum,
        int* __restrict__ off, float* __restrict__ inv_deg) {
    __shared__ int s[SCAN_CHUNK];
    int t = threadIdx.x;
    int i = blockIdx.x * SCAN_CHUNK + t;
    int d = (i < N_NODES) ? deg[i] : 0;
    s[t] = d;
    __syncthreads();
    #pragma unroll
    for (int o = 1; o < SCAN_CHUNK; o <<= 1) {
        int v = (t >= o) ? s[t - o] : 0;
        __syncthreads();
        s[t] += v;
        __syncthreads();
    }
    if (i < N_NODES) {
        off[i] = bsum[blockIdx.x] + s[t] - d;     // exclusive prefix
        inv_deg[i] = 1.0f / (float)max(d, 1);
    }
}

__global__ void fill_kernel(const int* __restrict__ src, const int* __restrict__ dst,
                            const int* __restrict__ off, int* __restrict__ cursor,
                            int* __restrict__ csr_src, int E) {
    int e = blockIdx.x * 256 + threadIdx.x;
    if (e < E) {
        int d = dst[e];
        int p = atomicAdd(&cursor[d], 1);
        csr_src[off[d] + p] = src[e];
    }
}

// ---------------- mean aggregation: one wave per node ----------------
// h row stride = OUT_STRIDE (h lives inside the output buffer)

__global__ void agg_kernel(const float* __restrict__ h,
                           const int* __restrict__ off, const int* __restrict__ deg,
                           const float* __restrict__ inv_deg,
                           const int* __restrict__ csr_src,
                           float* __restrict__ agg) {
    int wave = threadIdx.x >> 6;   // 0..3
    int lane = threadIdx.x & 63;
    int n = blockIdx.x * 4 + wave;
    if (n >= N_NODES) return;
    int start = off[n];
    int cnt = deg[n];
    float ax = 0.f, ay = 0.f;
    for (int e = 0; e < cnt; ++e) {
        int s = csr_src[start + e];
        const float2 v = *(const float2*)(h + (size_t)s * OUT_STRIDE + 2 * lane);
        ax += v.x; ay += v.y;
    }
    float sc = inv_deg[n];
    float2* o = (float2*)(agg + (size_t)n * HID) + lane;
    *o = make_float2(ax * sc, ay * sc);
}

// ---------------- GEMM + ReLU: C[:, coff:coff+128] = relu(A @ W) ----------------
// A: [nrows,128] contiguous. W: [128,128] k-major. C row stride OUT_STRIDE.
// Tile 64 rows x 64 cols per block (blockIdx.y = col half), 256 threads,
// 4x4 register micro-tile, A-tile + W-half staged in LDS (32KB + 32KB).

__global__ __launch_bounds__(256) void gemm_relu_kernel(
        const float* __restrict__ A, const float* __restrict__ W,
        float* __restrict__ C, int coff, int nrows) {
    __shared__ float Wl[128 * 64];   // [k][c-half]
    __shared__ float Al[64 * 128];   // [r][k]
    int tid = threadIdx.x;
    int r0 = blockIdx.x * 64;
    int ch = blockIdx.y;             // 0 or 1: column half

    // load W half: 8192 floats, 8 float4 per thread, coalesced
    #pragma unroll
    for (int i = 0; i < 8; ++i) {
        int o = i * 1024 + tid * 4;
        int k = o >> 6, c = o & 63;
        *(float4*)&Wl[o] = *(const float4*)&W[k * 128 + ch * 64 + c];
    }
    // load A tile: 8192 floats, guarded
    int limit = nrows * 128;
    #pragma unroll
    for (int i = 0; i < 8; ++i) {
        int o = i * 1024 + tid * 4;
        int g = r0 * 128 + o;
        float4 v = make_float4(0.f, 0.f, 0.f, 0.f);
        if (g < limit) v = *(const float4*)&A[g];
        *(float4*)&Al[o] = v;
    }
    __syncthreads();

    int cg = tid & 15;  int col = cg * 4;      // 16 col-groups x 4 cols = 64
    int rg = tid >> 4;                          // 16 row-groups x 4 rows = 64
    float acc[4][4] = {};

    for (int k = 0; k < 128; k += 4) {
        float4 w[4];
        #pragma unroll
        for (int kk = 0; kk < 4; ++kk)
            w[kk] = *(const float4*)&Wl[(k + kk) * 64 + col];
        #pragma unroll
        for (int j = 0; j < 4; ++j) {
            float4 a = *(const float4*)&Al[(rg * 4 + j) * 128 + k];
            float av[4] = {a.x, a.y, a.z, a.w};
            #pragma unroll
            for (int kk = 0; kk < 4; ++kk) {
                const float* wv = (const float*)&w[kk];
                acc[j][0] += av[kk] * wv[0];
                acc[j][1] += av[kk] * wv[1];
                acc[j][2] += av[kk] * wv[2];
                acc[j][3] += av[kk] * wv[3];
            }
        }
    }

    #pragma unroll
    for (int j = 0; j < 4; ++j) {
        int r = r0 + rg * 4 + j;
        if (r < nrows) {
            float4 o;
            o.x = fmaxf(acc[j][0], 0.f);
            o.y = fmaxf(acc[j][1], 0.f);
            o.z = fmaxf(acc[j][2], 0.f);
            o.w = fmaxf(acc[j][3], 0.f);
            *(float4*)&C[(size_t)r * OUT_STRIDE + coff + ch * 64 + col] = o;
        }
    }
}

extern "C" void kernel_launch(void* const* d_in, const int* in_sizes, int n_in,
                              void* d_out, int out_size, void* d_ws, size_t ws_size,
                              hipStream_t stream) {
    const float* feat = (const float*)d_in[0];
    const int*   src  = (const int*)d_in[1];
    const int*   dst  = (const int*)d_in[2];
    const float* W0   = (const float*)d_in[3];
    const float* Ws   = (const float*)d_in[4];
    float* out = (float*)d_out;

    // workspace carve-up (~29.6 MB)
    char* p = (char*)d_ws;
    float* agg   = (float*)p;           p += (size_t)N_NODES * HID * sizeof(float);
    int*   deg   = (int*)p;             p += (size_t)N_NODES * sizeof(int);
    int*   cursor= (int*)p;             p += (size_t)N_NODES * sizeof(int);
    int*   off   = (int*)p;             p += (size_t)N_NODES * sizeof(int);
    int*   csr   = (int*)p;             p += (size_t)N_EDGES * sizeof(int);
    float* invd  = (float*)p;           p += (size_t)N_NODES * sizeof(float);
    int*   bsum  = (int*)p;

    // deg and cursor are contiguous: zero both in one memset
    hipMemsetAsync(deg, 0, (size_t)N_NODES * 2 * sizeof(int), stream);

    int eblocks = (N_EDGES + 255) / 256;
    deg_kernel<<<eblocks, 256, 0, stream>>>(dst, deg, N_EDGES);
    blocksum_kernel<<<SCAN_BLOCKS, SCAN_CHUNK, 0, stream>>>(deg, bsum);
    scanb_kernel<<<1, 128, 0, stream>>>(bsum);
    scanfin_kernel<<<SCAN_BLOCKS, SCAN_CHUNK, 0, stream>>>(deg, bsum, off, invd);
    fill_kernel<<<eblocks, 256, 0, stream>>>(src, dst, off, cursor, csr, N_EDGES);

    dim3 ggrid((N_NODES + 63) / 64, 2);
    // h0 = relu(feat @ W0) -> out[:, 0:128]
    gemm_relu_kernel<<<ggrid, 256, 0, stream>>>(feat, W0, out, 0, N_NODES);

    int ablocks = (N_NODES + 3) / 4;
    for (int l = 0; l < 3; ++l) {
        agg_kernel<<<ablocks, 256, 0, stream>>>(out + l * HID, off, deg, invd, csr, agg);
        gemm_relu_kernel<<<ggrid, 256, 0, stream>>>(agg, Ws + (size_t)l * HID * HID,
                                                    out, (l + 1) * HID, N_NODES);
    }
}

// Round 3
// 349.420 us; speedup vs baseline: 1.7074x; 1.4152x over previous
//
#include <hip/hip_runtime.h>

#define N_NODES 50000
#define N_EDGES 800000
#define HID 128
#define OUT_STRIDE 512

#define SCAN_CHUNK 512
#define SCAN_BLOCKS ((N_NODES + SCAN_CHUNK - 1) / SCAN_CHUNK)   // 98

typedef __attribute__((ext_vector_type(8))) short short8;
typedef __attribute__((ext_vector_type(4))) float f32x4;

__device__ __forceinline__ unsigned short f2bf(float f) {
    unsigned int u = __float_as_uint(f);
    u += 0x7FFF + ((u >> 16) & 1);          // round-to-nearest-even
    return (unsigned short)(u >> 16);
}

// ---------------- CSR build ----------------

__global__ void deg_kernel(const int* __restrict__ dst, int* __restrict__ deg, int E) {
    int e = blockIdx.x * 256 + threadIdx.x;
    if (e < E) atomicAdd(&deg[dst[e]], 1);
}

__global__ __launch_bounds__(SCAN_CHUNK) void blocksum_kernel(
        const int* __restrict__ deg, int* __restrict__ bsum) {
    __shared__ int ws[SCAN_CHUNK / 64];
    int i = blockIdx.x * SCAN_CHUNK + threadIdx.x;
    int v = (i < N_NODES) ? deg[i] : 0;
    #pragma unroll
    for (int o = 32; o > 0; o >>= 1) v += __shfl_down(v, o, 64);
    if ((threadIdx.x & 63) == 0) ws[threadIdx.x >> 6] = v;
    __syncthreads();
    if (threadIdx.x == 0) {
        int s = 0;
        #pragma unroll
        for (int w = 0; w < SCAN_CHUNK / 64; ++w) s += ws[w];
        bsum[blockIdx.x] = s;
    }
}

__global__ void scanb_kernel(int* __restrict__ bsum) {
    __shared__ int s[128];
    int t = threadIdx.x;
    s[t] = (t < SCAN_BLOCKS) ? bsum[t] : 0;
    __syncthreads();
    #pragma unroll
    for (int o = 1; o < 128; o <<= 1) {
        int v = (t >= o) ? s[t - o] : 0;
        __syncthreads();
        s[t] += v;
        __syncthreads();
    }
    if (t < SCAN_BLOCKS) bsum[t] = (t == 0) ? 0 : s[t - 1];
}

__global__ __launch_bounds__(SCAN_CHUNK) void scanfin_kernel(
        const int* __restrict__ deg, const int* __restrict__ bsum,
        int* __restrict__ off, float* __restrict__ inv_deg) {
    __shared__ int s[SCAN_CHUNK];
    int t = threadIdx.x;
    int i = blockIdx.x * SCAN_CHUNK + t;
    int d = (i < N_NODES) ? deg[i] : 0;
    s[t] = d;
    __syncthreads();
    #pragma unroll
    for (int o = 1; o < SCAN_CHUNK; o <<= 1) {
        int v = (t >= o) ? s[t - o] : 0;
        __syncthreads();
        s[t] += v;
        __syncthreads();
    }
    if (i < N_NODES) {
        off[i] = bsum[blockIdx.x] + s[t] - d;
        inv_deg[i] = 1.0f / (float)max(d, 1);
    }
}

__global__ void fill_kernel(const int* __restrict__ src, const int* __restrict__ dst,
                            const int* __restrict__ off, int* __restrict__ cursor,
                            int* __restrict__ csr_src, int E) {
    int e = blockIdx.x * 256 + threadIdx.x;
    if (e < E) {
        int d = dst[e];
        int p = atomicAdd(&cursor[d], 1);
        csr_src[off[d] + p] = src[e];
    }
}

// ---------------- dtype prep ----------------

// feat f32 -> bf16, 4 elems/thread
__global__ void cvt_feat_kernel(const float* __restrict__ f, unsigned short* __restrict__ o,
                                int n4) {
    int i = blockIdx.x * 256 + threadIdx.x;
    if (i < n4) {
        float4 v = ((const float4*)f)[i];
        ushort4 r;
        r.x = f2bf(v.x); r.y = f2bf(v.y); r.z = f2bf(v.z); r.w = f2bf(v.w);
        ((ushort4*)o)[i] = r;
    }
}

// Wt[m][c][k] = W_m[k][c] in bf16 (m=0: W0, m=1..3: Ws[m-1])
__global__ void prep_w_kernel(const float* __restrict__ W0, const float* __restrict__ Ws,
                              unsigned short* __restrict__ Wt) {
    int m = blockIdx.x;
    const float* S = (m == 0) ? W0 : Ws + (size_t)(m - 1) * 16384;
    for (int it = 0; it < 64; ++it) {
        int idx = it * 256 + threadIdx.x;
        int k = idx >> 7, c = idx & 127;
        Wt[(size_t)m * 16384 + c * 128 + k] = f2bf(S[idx]);
    }
}

// ---------------- mean aggregation: one wave per node, bf16 gather ----------------

__global__ __launch_bounds__(256) void agg_kernel(
        const unsigned short* __restrict__ hb, const int* __restrict__ off,
        const int* __restrict__ deg, const float* __restrict__ invd,
        const int* __restrict__ csr, unsigned short* __restrict__ aggb) {
    int wave = threadIdx.x >> 6;
    int lane = threadIdx.x & 63;
    int n = blockIdx.x * 4 + wave;
    if (n >= N_NODES) return;
    int start = off[n], cnt = deg[n];
    float ax = 0.f, ay = 0.f, bx = 0.f, by = 0.f;
    int e = 0;
    for (; e + 2 <= cnt; e += 2) {
        int s0 = csr[start + e];
        int s1 = csr[start + e + 1];
        unsigned int v0 = *(const unsigned int*)(hb + (size_t)s0 * 128 + 2 * lane);
        unsigned int v1 = *(const unsigned int*)(hb + (size_t)s1 * 128 + 2 * lane);
        ax += __uint_as_float(v0 << 16);
        ay += __uint_as_float(v0 & 0xFFFF0000u);
        bx += __uint_as_float(v1 << 16);
        by += __uint_as_float(v1 & 0xFFFF0000u);
    }
    if (e < cnt) {
        int s0 = csr[start + e];
        unsigned int v0 = *(const unsigned int*)(hb + (size_t)s0 * 128 + 2 * lane);
        ax += __uint_as_float(v0 << 16);
        ay += __uint_as_float(v0 & 0xFFFF0000u);
    }
    float sc = invd[n];
    ax = (ax + bx) * sc;
    ay = (ay + by) * sc;
    unsigned int pack = (unsigned int)f2bf(ax) | ((unsigned int)f2bf(ay) << 16);
    *(unsigned int*)(aggb + (size_t)n * 128 + 2 * lane) = pack;
}

// ---------------- MFMA GEMM + ReLU ----------------
// C[:, coff:coff+128] = relu(A @ W), A: [nrows][128] bf16, Wt: [c][k] bf16.
// Block = 4 waves, each wave: 16 rows x 128 cols, K=128 in 4 steps of 32.
// A/B fragments use IDENTICAL (kg, j)->k arithmetic, so any HW k-permutation
// cancels (A/B layouts are mutual transposes). C/D mapping is the verified
// col=lane&15, row=(lane>>4)*4+reg.

__global__ __launch_bounds__(256) void gemm_mfma_kernel(
        const unsigned short* __restrict__ A, const unsigned short* __restrict__ Wt,
        float* __restrict__ Cout, unsigned short* __restrict__ Hb,
        int coff, int nrows) {
    int wave = threadIdx.x >> 6;
    int lane = threadIdx.x & 63;
    int r0 = blockIdx.x * 64 + wave * 16;
    int m15 = lane & 15;
    int kg = lane >> 4;

    int ar = r0 + m15;
    if (ar >= nrows) ar = nrows - 1;          // clamp; stores are masked
    const unsigned short* arow = A + (size_t)ar * 128 + kg * 8;
    short8 af[4];
    #pragma unroll
    for (int ks = 0; ks < 4; ++ks)
        af[ks] = *(const short8*)(arow + ks * 32);

    f32x4 acc[8];
    #pragma unroll
    for (int nf = 0; nf < 8; ++nf) acc[nf] = (f32x4){0.f, 0.f, 0.f, 0.f};

    #pragma unroll
    for (int nf = 0; nf < 8; ++nf) {
        const unsigned short* wrow = Wt + (size_t)(nf * 16 + m15) * 128 + kg * 8;
        #pragma unroll
        for (int ks = 0; ks < 4; ++ks) {
            short8 bf = *(const short8*)(wrow + ks * 32);
            acc[nf] = __builtin_amdgcn_mfma_f32_16x16x32_bf16(af[ks], bf, acc[nf], 0, 0, 0);
        }
    }

    #pragma unroll
    for (int j = 0; j < 4; ++j) {
        int orow = r0 + kg * 4 + j;
        if (orow < nrows) {
            size_t cb = (size_t)orow * OUT_STRIDE + coff + m15;
            size_t hoff = (size_t)orow * 128 + m15;
            #pragma unroll
            for (int nf = 0; nf < 8; ++nf) {
                float v = fmaxf(acc[nf][j], 0.f);
                Cout[cb + nf * 16] = v;
                if (Hb) Hb[hoff + nf * 16] = f2bf(v);
            }
        }
    }
}

extern "C" void kernel_launch(void* const* d_in, const int* in_sizes, int n_in,
                              void* d_out, int out_size, void* d_ws, size_t ws_size,
                              hipStream_t stream) {
    const float* feat = (const float*)d_in[0];
    const int*   src  = (const int*)d_in[1];
    const int*   dst  = (const int*)d_in[2];
    const float* W0   = (const float*)d_in[3];
    const float* Ws   = (const float*)d_in[4];
    float* out = (float*)d_out;

    // workspace carve-up (~29.7 MB, <= proven-safe R2 usage)
    char* p = (char*)d_ws;
    unsigned short* featb = (unsigned short*)p;  p += (size_t)N_NODES * HID * 2; // also aggb
    unsigned short* hb    = (unsigned short*)p;  p += (size_t)N_NODES * HID * 2;
    unsigned short* Wt    = (unsigned short*)p;  p += (size_t)4 * HID * HID * 2;
    int*   deg    = (int*)p;                     p += (size_t)N_NODES * 4;
    int*   cursor = (int*)p;                     p += (size_t)N_NODES * 4;
    int*   off    = (int*)p;                     p += (size_t)N_NODES * 4;
    float* invd   = (float*)p;                   p += (size_t)N_NODES * 4;
    int*   csr    = (int*)p;                     p += (size_t)N_EDGES * 4;
    int*   bsum   = (int*)p;
    unsigned short* aggb = featb;                // featb dead after GEMM0

    hipMemsetAsync(deg, 0, (size_t)N_NODES * 2 * sizeof(int), stream);

    int eblocks = (N_EDGES + 255) / 256;
    deg_kernel<<<eblocks, 256, 0, stream>>>(dst, deg, N_EDGES);
    blocksum_kernel<<<SCAN_BLOCKS, SCAN_CHUNK, 0, stream>>>(deg, bsum);
    scanb_kernel<<<1, 128, 0, stream>>>(bsum);
    scanfin_kernel<<<SCAN_BLOCKS, SCAN_CHUNK, 0, stream>>>(deg, bsum, off, invd);
    fill_kernel<<<eblocks, 256, 0, stream>>>(src, dst, off, cursor, csr, N_EDGES);

    int n4 = N_NODES * HID / 4;
    cvt_feat_kernel<<<(n4 + 255) / 256, 256, 0, stream>>>(feat, featb, n4);
    prep_w_kernel<<<4, 256, 0, stream>>>(W0, Ws, Wt);

    int gblocks = (N_NODES + 63) / 64;
    // h0 = relu(feat @ W0) -> out[:,0:128] (f32) and hb (bf16)
    gemm_mfma_kernel<<<gblocks, 256, 0, stream>>>(featb, Wt, out, hb, 0, N_NODES);

    int ablocks = (N_NODES + 3) / 4;
    for (int l = 0; l < 3; ++l) {
        agg_kernel<<<ablocks, 256, 0, stream>>>(hb, off, deg, invd, csr, aggb);
        gemm_mfma_kernel<<<gblocks, 256, 0, stream>>>(
            aggb, Wt + (size_t)(l + 1) * HID * HID, out, (l == 2) ? nullptr : hb,
            (l + 1) * HID, N_NODES);
    }
}

// Round 4
// 309.659 us; speedup vs baseline: 1.9267x; 1.1284x over previous
//
#include <hip/hip_runtime.h>

#define N_NODES 50000
#define N_EDGES 800000
#define HID 128
#define OUT_STRIDE 512

#define SCAN_CHUNK 512
#define SCAN_BLOCKS ((N_NODES + SCAN_CHUNK - 1) / SCAN_CHUNK)   // 98

typedef __attribute__((ext_vector_type(8))) short short8;
typedef __attribute__((ext_vector_type(4))) float f32x4;

__device__ __forceinline__ unsigned short f2bf(float f) {
    unsigned int u = __float_as_uint(f);
    u += 0x7FFF + ((u >> 16) & 1);          // round-to-nearest-even
    return (unsigned short)(u >> 16);
}

// ---------------- CSR build ----------------

__global__ void deg_kernel(const int* __restrict__ dst, int* __restrict__ deg, int E) {
    int e = blockIdx.x * 256 + threadIdx.x;
    if (e < E) atomicAdd(&deg[dst[e]], 1);
}

__global__ __launch_bounds__(SCAN_CHUNK) void blocksum_kernel(
        const int* __restrict__ deg, int* __restrict__ bsum) {
    __shared__ int ws[SCAN_CHUNK / 64];
    int i = blockIdx.x * SCAN_CHUNK + threadIdx.x;
    int v = (i < N_NODES) ? deg[i] : 0;
    #pragma unroll
    for (int o = 32; o > 0; o >>= 1) v += __shfl_down(v, o, 64);
    if ((threadIdx.x & 63) == 0) ws[threadIdx.x >> 6] = v;
    __syncthreads();
    if (threadIdx.x == 0) {
        int s = 0;
        #pragma unroll
        for (int w = 0; w < SCAN_CHUNK / 64; ++w) s += ws[w];
        bsum[blockIdx.x] = s;
    }
}

__global__ void scanb_kernel(int* __restrict__ bsum) {
    __shared__ int s[128];
    int t = threadIdx.x;
    s[t] = (t < SCAN_BLOCKS) ? bsum[t] : 0;
    __syncthreads();
    #pragma unroll
    for (int o = 1; o < 128; o <<= 1) {
        int v = (t >= o) ? s[t - o] : 0;
        __syncthreads();
        s[t] += v;
        __syncthreads();
    }
    if (t < SCAN_BLOCKS) bsum[t] = (t == 0) ? 0 : s[t - 1];
}

__global__ __launch_bounds__(SCAN_CHUNK) void scanfin_kernel(
        const int* __restrict__ deg, const int* __restrict__ bsum,
        int* __restrict__ off, float* __restrict__ inv_deg) {
    __shared__ int s[SCAN_CHUNK];
    int t = threadIdx.x;
    int i = blockIdx.x * SCAN_CHUNK + t;
    int d = (i < N_NODES) ? deg[i] : 0;
    s[t] = d;
    __syncthreads();
    #pragma unroll
    for (int o = 1; o < SCAN_CHUNK; o <<= 1) {
        int v = (t >= o) ? s[t - o] : 0;
        __syncthreads();
        s[t] += v;
        __syncthreads();
    }
    if (i < N_NODES) {
        off[i] = bsum[blockIdx.x] + s[t] - d;
        inv_deg[i] = 1.0f / (float)max(d, 1);
    }
}

__global__ void fill_kernel(const int* __restrict__ src, const int* __restrict__ dst,
                            const int* __restrict__ off, int* __restrict__ cursor,
                            int* __restrict__ csr_src, int E) {
    int e = blockIdx.x * 256 + threadIdx.x;
    if (e < E) {
        int d = dst[e];
        int p = atomicAdd(&cursor[d], 1);
        csr_src[off[d] + p] = src[e];
    }
}

// ---------------- dtype prep (fused feat-cvt + W-transpose) ----------------
// blocks [0, FB): feat f32 -> bf16, 4 elems/thread
// blocks [FB, FB+4): Wt[m][c][k] = W_m[k][c] bf16

#define FB ((N_NODES * HID / 4 + 255) / 256)   // 6250

__global__ void prep_kernel(const float* __restrict__ f, const float* __restrict__ W0,
                            const float* __restrict__ Ws, unsigned short* __restrict__ o,
                            unsigned short* __restrict__ Wt) {
    int b = blockIdx.x;
    if (b < FB) {
        int i = b * 256 + threadIdx.x;
        if (i < N_NODES * HID / 4) {
            float4 v = ((const float4*)f)[i];
            ushort4 r;
            r.x = f2bf(v.x); r.y = f2bf(v.y); r.z = f2bf(v.z); r.w = f2bf(v.w);
            ((ushort4*)o)[i] = r;
        }
    } else {
        int m = b - FB;
        const float* S = (m == 0) ? W0 : Ws + (size_t)(m - 1) * 16384;
        for (int it = 0; it < 64; ++it) {
            int idx = it * 256 + threadIdx.x;
            int k = idx >> 7, c = idx & 127;
            Wt[(size_t)m * 16384 + c * 128 + k] = f2bf(S[idx]);
        }
    }
}

// ---------------- mean aggregation ----------------
// One wave per node. Wave split in two 32-lane halves; each half reads one
// full 256B row (uint2 = 4 bf16 per lane). x2 unroll -> 4 edge-rows in
// flight per wave. Cross-half combine via shfl_xor(32).

__global__ __launch_bounds__(256) void agg_kernel(
        const unsigned short* __restrict__ hb, const int* __restrict__ off,
        const int* __restrict__ deg, const float* __restrict__ invd,
        const int* __restrict__ csr, unsigned short* __restrict__ aggb) {
    int wave = threadIdx.x >> 6;
    int lane = threadIdx.x & 63;
    int n = blockIdx.x * 4 + wave;
    if (n >= N_NODES) return;
    int start = off[n], cnt = deg[n];
    int half = lane >> 5;          // which edge of the pair
    int q = lane & 31;             // dims 4q..4q+3
    const unsigned short* base = hb + q * 4;

    float a0 = 0.f, a1 = 0.f, a2 = 0.f, a3 = 0.f;
    float b0 = 0.f, b1 = 0.f, b2 = 0.f, b3 = 0.f;
    int e = 0;
    for (; e + 4 <= cnt; e += 4) {
        int sA = csr[start + e + half];
        int sB = csr[start + e + 2 + half];
        uint2 vA = *(const uint2*)(base + (unsigned)sA * 128u);
        uint2 vB = *(const uint2*)(base + (unsigned)sB * 128u);
        a0 += __uint_as_float(vA.x << 16);
        a1 += __uint_as_float(vA.x & 0xFFFF0000u);
        a2 += __uint_as_float(vA.y << 16);
        a3 += __uint_as_float(vA.y & 0xFFFF0000u);
        b0 += __uint_as_float(vB.x << 16);
        b1 += __uint_as_float(vB.x & 0xFFFF0000u);
        b2 += __uint_as_float(vB.y << 16);
        b3 += __uint_as_float(vB.y & 0xFFFF0000u);
    }
    if (e + 2 <= cnt) {
        int sA = csr[start + e + half];
        uint2 vA = *(const uint2*)(base + (unsigned)sA * 128u);
        a0 += __uint_as_float(vA.x << 16);
        a1 += __uint_as_float(vA.x & 0xFFFF0000u);
        a2 += __uint_as_float(vA.y << 16);
        a3 += __uint_as_float(vA.y & 0xFFFF0000u);
        e += 2;
    }
    if (e < cnt && half == 0) {    // odd tail: first half only
        int sA = csr[start + e];
        uint2 vA = *(const uint2*)(base + (unsigned)sA * 128u);
        a0 += __uint_as_float(vA.x << 16);
        a1 += __uint_as_float(vA.x & 0xFFFF0000u);
        a2 += __uint_as_float(vA.y << 16);
        a3 += __uint_as_float(vA.y & 0xFFFF0000u);
    }
    a0 += b0; a1 += b1; a2 += b2; a3 += b3;
    a0 += __shfl_xor(a0, 32);
    a1 += __shfl_xor(a1, 32);
    a2 += __shfl_xor(a2, 32);
    a3 += __shfl_xor(a3, 32);
    if (half == 0) {
        float sc = invd[n];
        a0 *= sc; a1 *= sc; a2 *= sc; a3 *= sc;
        unsigned int p0 = (unsigned int)f2bf(a0) | ((unsigned int)f2bf(a1) << 16);
        unsigned int p1 = (unsigned int)f2bf(a2) | ((unsigned int)f2bf(a3) << 16);
        *(uint2*)(aggb + (unsigned)n * 128u + q * 4) = make_uint2(p0, p1);
    }
}

// ---------------- MFMA GEMM + ReLU ----------------
// C[:, coff:coff+128] = relu(A @ W), A: [nrows][128] bf16, Wt: [c][k] bf16.
// Block = 4 waves, each wave: 16 rows x 128 cols, K=128 in 4 steps of 32.
// A/B fragments use IDENTICAL (kg, j)->k arithmetic, so any HW k-permutation
// cancels. C/D mapping: col=lane&15, row=(lane>>4)*4+reg (HW-verified).

__global__ __launch_bounds__(256) void gemm_mfma_kernel(
        const unsigned short* __restrict__ A, const unsigned short* __restrict__ Wt,
        float* __restrict__ Cout, unsigned short* __restrict__ Hb,
        int coff, int nrows) {
    int wave = threadIdx.x >> 6;
    int lane = threadIdx.x & 63;
    int r0 = blockIdx.x * 64 + wave * 16;
    int m15 = lane & 15;
    int kg = lane >> 4;

    int ar = r0 + m15;
    if (ar >= nrows) ar = nrows - 1;          // clamp; stores are masked
    const unsigned short* arow = A + (size_t)ar * 128 + kg * 8;
    short8 af[4];
    #pragma unroll
    for (int ks = 0; ks < 4; ++ks)
        af[ks] = *(const short8*)(arow + ks * 32);

    f32x4 acc[8];
    #pragma unroll
    for (int nf = 0; nf < 8; ++nf) acc[nf] = (f32x4){0.f, 0.f, 0.f, 0.f};

    #pragma unroll
    for (int nf = 0; nf < 8; ++nf) {
        const unsigned short* wrow = Wt + (size_t)(nf * 16 + m15) * 128 + kg * 8;
        #pragma unroll
        for (int ks = 0; ks < 4; ++ks) {
            short8 bf = *(const short8*)(wrow + ks * 32);
            acc[nf] = __builtin_amdgcn_mfma_f32_16x16x32_bf16(af[ks], bf, acc[nf], 0, 0, 0);
        }
    }

    #pragma unroll
    for (int j = 0; j < 4; ++j) {
        int orow = r0 + kg * 4 + j;
        if (orow < nrows) {
            size_t cb = (size_t)orow * OUT_STRIDE + coff + m15;
            size_t hoff = (size_t)orow * 128 + m15;
            #pragma unroll
            for (int nf = 0; nf < 8; ++nf) {
                float v = fmaxf(acc[nf][j], 0.f);
                Cout[cb + nf * 16] = v;
                if (Hb) Hb[hoff + nf * 16] = f2bf(v);
            }
        }
    }
}

extern "C" void kernel_launch(void* const* d_in, const int* in_sizes, int n_in,
                              void* d_out, int out_size, void* d_ws, size_t ws_size,
                              hipStream_t stream) {
    const float* feat = (const float*)d_in[0];
    const int*   src  = (const int*)d_in[1];
    const int*   dst  = (const int*)d_in[2];
    const float* W0   = (const float*)d_in[3];
    const float* Ws   = (const float*)d_in[4];
    float* out = (float*)d_out;

    // workspace carve-up (~29.7 MB)
    char* p = (char*)d_ws;
    unsigned short* featb = (unsigned short*)p;  p += (size_t)N_NODES * HID * 2; // also aggb
    unsigned short* hb    = (unsigned short*)p;  p += (size_t)N_NODES * HID * 2;
    unsigned short* Wt    = (unsigned short*)p;  p += (size_t)4 * HID * HID * 2;
    int*   deg    = (int*)p;                     p += (size_t)N_NODES * 4;
    int*   cursor = (int*)p;                     p += (size_t)N_NODES * 4;
    int*   off    = (int*)p;                     p += (size_t)N_NODES * 4;
    float* invd   = (float*)p;                   p += (size_t)N_NODES * 4;
    int*   csr    = (int*)p;                     p += (size_t)N_EDGES * 4;
    int*   bsum   = (int*)p;
    unsigned short* aggb = featb;                // featb dead after GEMM0

    hipMemsetAsync(deg, 0, (size_t)N_NODES * 2 * sizeof(int), stream);

    int eblocks = (N_EDGES + 255) / 256;
    deg_kernel<<<eblocks, 256, 0, stream>>>(dst, deg, N_EDGES);
    blocksum_kernel<<<SCAN_BLOCKS, SCAN_CHUNK, 0, stream>>>(deg, bsum);
    scanb_kernel<<<1, 128, 0, stream>>>(bsum);
    scanfin_kernel<<<SCAN_BLOCKS, SCAN_CHUNK, 0, stream>>>(deg, bsum, off, invd);
    fill_kernel<<<eblocks, 256, 0, stream>>>(src, dst, off, cursor, csr, N_EDGES);

    prep_kernel<<<FB + 4, 256, 0, stream>>>(feat, W0, Ws, featb, Wt);

    int gblocks = (N_NODES + 63) / 64;
    gemm_mfma_kernel<<<gblocks, 256, 0, stream>>>(featb, Wt, out, hb, 0, N_NODES);

    int ablocks = (N_NODES + 3) / 4;
    for (int l = 0; l < 3; ++l) {
        agg_kernel<<<ablocks, 256, 0, stream>>>(hb, off, deg, invd, csr, aggb);
        gemm_mfma_kernel<<<gblocks, 256, 0, stream>>>(
            aggb, Wt + (size_t)(l + 1) * HID * HID, out, (l == 2) ? nullptr : hb,
            (l + 1) * HID, N_NODES);
    }
}